// Round 13
// baseline (464.183 us; speedup 1.0000x reference)
//
#include <hip/hip_runtime.h>
#include <hip/hip_bf16.h>
#include <hip/hip_fp8.h>

// Sinkhorn on MI355X. B=64, L=1024, D=256.
// K stored as fp8-e4m3 plane K8 (64MB) + fp8 relative-residual plane R8 (64MB):
//   K_rec = dec(K8) * (1 + dec(R8))  ~= fp16 accuracy (0.2%).
// gemm (BK=32; fp32 tiles DMA'd via global_load_lds, swizzled source, linear
//   LDS; fp32->bf16 at fragment read; norms from fragment sumsq via shfl;
//   swapped-operand MFMA; packed-u32 fp8 direct stores; colsum p0)
//   -> passes 1..9 fused1024 (fp8; pass1 reads 8-strip p0, rest 4-strip)
//   -> pass 10 fused512 reconstructed (z + G minmax)
//   -> fin (out = minmax-norm(u*K_rec*v^T) * (-log K_rec))
// R13: gemm staging de-latencied (no VGPR roundtrip, no staging VALU);
// pass 9 fp8-only (recon only needed for final z/minmax/fin).
// WS_NEED = 135791104 <= proven-available 136053248.

#define EPSV 1e-12f
#define W1 0.0009765625f   // 1/1024

typedef short  short8 __attribute__((ext_vector_type(8)));
typedef float  f32x4  __attribute__((ext_vector_type(4)));
typedef float  f32x2v __attribute__((ext_vector_type(2)));

// ---- fast math helpers ----
__device__ __forceinline__ float rcpf_(float x) {
#if __has_builtin(__builtin_amdgcn_rcpf)
  return __builtin_amdgcn_rcpf(x);
#else
  return 1.0f / x;
#endif
}
__device__ __forceinline__ float rsqf_(float x) {
#if __has_builtin(__builtin_amdgcn_rsqf)
  return __builtin_amdgcn_rsqf(x);
#else
  return rsqrtf(x);
#endif
}

// ---- direct global->LDS DMA (16B per lane). l must be wave-uniform. ----
__device__ __forceinline__ void dma16(const float* g, float* l, int laneByte) {
#if __has_builtin(__builtin_amdgcn_global_load_lds)
  __builtin_amdgcn_global_load_lds(
      (const __attribute__((address_space(1))) unsigned*)g,
      (__attribute__((address_space(3))) unsigned*)l, 16, 0, 0);
#else
  *(float4*)((char*)l + laneByte) = *(const float4*)g;
#endif
}

// ---- fp8 e4m3 helpers ----
__device__ __forceinline__ unsigned char enc1(float x) {
#if __has_builtin(__builtin_amdgcn_cvt_pk_fp8_f32)
  int v = __builtin_amdgcn_cvt_pk_fp8_f32(x, x, 0, false);
  return (unsigned char)(v & 0xff);
#else
  __hip_fp8_e4m3 q(x); return (unsigned char)q.__x;
#endif
}
__device__ __forceinline__ float dec1(unsigned char b) {
#if __has_builtin(__builtin_amdgcn_cvt_f32_fp8)
  return __builtin_amdgcn_cvt_f32_fp8((int)b, 0);
#else
  __hip_fp8_e4m3 q; q.__x = (__hip_fp8_storage_t)b; return (float)q;
#endif
}
__device__ __forceinline__ unsigned pack4fp8(float a, float b, float c, float d) {
#if __has_builtin(__builtin_amdgcn_cvt_pk_fp8_f32)
  int v = __builtin_amdgcn_cvt_pk_fp8_f32(a, b, 0, false);
  v = __builtin_amdgcn_cvt_pk_fp8_f32(c, d, v, true);
  return (unsigned)v;
#else
  return (unsigned)enc1(a) | ((unsigned)enc1(b) << 8) |
         ((unsigned)enc1(c) << 16) | ((unsigned)enc1(d) << 24);
#endif
}
__device__ __forceinline__ void unpack4fp8(unsigned v, float* f) {
#if __has_builtin(__builtin_amdgcn_cvt_pk_f32_fp8)
  f32x2v p;
  p = __builtin_amdgcn_cvt_pk_f32_fp8((int)v, false); f[0] = p[0]; f[1] = p[1];
  p = __builtin_amdgcn_cvt_pk_f32_fp8((int)v, true);  f[2] = p[0]; f[3] = p[1];
#else
  #pragma unroll
  for (int i = 0; i < 4; ++i) f[i] = dec1((unsigned char)((v >> (i * 8)) & 0xff));
#endif
}
__device__ __forceinline__ void decode16(uint4 d, float* f) {
  unpack4fp8(d.x, f); unpack4fp8(d.y, f + 4);
  unpack4fp8(d.z, f + 8); unpack4fp8(d.w, f + 12);
}
__device__ __forceinline__ float dot16u(uint4 d, const float* s) {
#if __has_builtin(__builtin_amdgcn_cvt_pk_f32_fp8)
  f32x2v p; float a = 0.f;
  p = __builtin_amdgcn_cvt_pk_f32_fp8((int)d.x, false); a += p[0]*s[0]  + p[1]*s[1];
  p = __builtin_amdgcn_cvt_pk_f32_fp8((int)d.x, true);  a += p[0]*s[2]  + p[1]*s[3];
  p = __builtin_amdgcn_cvt_pk_f32_fp8((int)d.y, false); a += p[0]*s[4]  + p[1]*s[5];
  p = __builtin_amdgcn_cvt_pk_f32_fp8((int)d.y, true);  a += p[0]*s[6]  + p[1]*s[7];
  p = __builtin_amdgcn_cvt_pk_f32_fp8((int)d.z, false); a += p[0]*s[8]  + p[1]*s[9];
  p = __builtin_amdgcn_cvt_pk_f32_fp8((int)d.z, true);  a += p[0]*s[10] + p[1]*s[11];
  p = __builtin_amdgcn_cvt_pk_f32_fp8((int)d.w, false); a += p[0]*s[12] + p[1]*s[13];
  p = __builtin_amdgcn_cvt_pk_f32_fp8((int)d.w, true);  a += p[0]*s[14] + p[1]*s[15];
  return a;
#else
  float f[16]; decode16(d, f);
  float a = 0.f;
  #pragma unroll
  for (int k = 0; k < 16; ++k) a += f[k] * s[k];
  return a;
#endif
}
__device__ __forceinline__ void axpy16u(uint4 d, float u, float* pacc) {
#if __has_builtin(__builtin_amdgcn_cvt_pk_f32_fp8)
  f32x2v p;
  p = __builtin_amdgcn_cvt_pk_f32_fp8((int)d.x, false); pacc[0]  += p[0]*u; pacc[1]  += p[1]*u;
  p = __builtin_amdgcn_cvt_pk_f32_fp8((int)d.x, true);  pacc[2]  += p[0]*u; pacc[3]  += p[1]*u;
  p = __builtin_amdgcn_cvt_pk_f32_fp8((int)d.y, false); pacc[4]  += p[0]*u; pacc[5]  += p[1]*u;
  p = __builtin_amdgcn_cvt_pk_f32_fp8((int)d.y, true);  pacc[6]  += p[0]*u; pacc[7]  += p[1]*u;
  p = __builtin_amdgcn_cvt_pk_f32_fp8((int)d.z, false); pacc[8]  += p[0]*u; pacc[9]  += p[1]*u;
  p = __builtin_amdgcn_cvt_pk_f32_fp8((int)d.z, true);  pacc[10] += p[0]*u; pacc[11] += p[1]*u;
  p = __builtin_amdgcn_cvt_pk_f32_fp8((int)d.w, false); pacc[12] += p[0]*u; pacc[13] += p[1]*u;
  p = __builtin_amdgcn_cvt_pk_f32_fp8((int)d.w, true);  pacc[14] += p[0]*u; pacc[15] += p[1]*u;
#else
  float f[16]; decode16(d, f);
  #pragma unroll
  for (int k = 0; k < 16; ++k) pacc[k] += f[k] * u;
#endif
}

// two float4 -> 8 bf16 (as short8), hw v_cvt_pk_bf16_f32
__device__ __forceinline__ short8 cvt8f(float4 f0, float4 f1) {
  float2 p0; p0.x = f0.x; p0.y = f0.y;
  float2 p1; p1.x = f0.z; p1.y = f0.w;
  float2 p2; p2.x = f1.x; p2.y = f1.y;
  float2 p3; p3.x = f1.z; p3.y = f1.w;
  __hip_bfloat162 h0 = __float22bfloat162_rn(p0);
  __hip_bfloat162 h1 = __float22bfloat162_rn(p1);
  __hip_bfloat162 h2_ = __float22bfloat162_rn(p2);
  __hip_bfloat162 h3 = __float22bfloat162_rn(p3);
  short2 a = *(short2*)&h0, b = *(short2*)&h1, c = *(short2*)&h2_, d = *(short2*)&h3;
  short8 r;
  r[0] = a.x; r[1] = a.y; r[2] = b.x; r[3] = b.y;
  r[4] = c.x; r[5] = c.y; r[6] = d.x; r[7] = d.y;
  return r;
}

// ---------------------------------------------------------------- diag
__global__ __launch_bounds__(256) void diag_kernel(float* __restrict__ out,
                                                   float val, int n) {
  int stride = gridDim.x * 256;
  for (int i = blockIdx.x * 256 + threadIdx.x; i < n; i += stride) out[i] = val;
}

// ---------------------------------------------------------------- gemm
// 128x128 tile, BK=32 (8 rounds), 4 waves (2x2 of 64x64).
// fp32 tiles DMA'd to LDS (linear dest, source pieces pre-swizzled:
// lds piece p of row r holds global piece p ^ ((r&3)<<1)).
// Fragment read at chunk c^(r&3) -> contiguous 32B; cvt to bf16 in reg.
// Swapped-operand MFMA (R12 layout, refcheck-proven).
__global__ __launch_bounds__(256) void gemm_kernel(
    const float* __restrict__ x1, const float* __restrict__ x2,
    unsigned char* __restrict__ K8g, unsigned char* __restrict__ R8g,
    unsigned* __restrict__ mm, _Float16* __restrict__ p0) {
  __shared__ __align__(16) float As[128 * 32];   // 16 KB
  __shared__ __align__(16) float Bs[128 * 32];   // 16 KB
  __shared__ float bsq[128];
  __shared__ float csum[4][128];
  int bid = blockIdx.x;
  int b = bid >> 6, tile = bid & 63;
  int ti = (tile >> 3) << 7, tj = (tile & 7) << 7;
  int t = threadIdx.x, lane = t & 63, wave = t >> 6;
  int wr = (wave >> 1) << 6, wc = (wave & 1) << 6;
  const float* Ag = x1 + ((size_t)(b * 1024 + ti)) * 256;
  const float* Bg = x2 + ((size_t)(b * 1024 + tj)) * 256;

  if (bid == 0 && t < 128) mm[t] = (t < 64) ? 0u : 0x7f800000u;

  f32x4 acc[4][4];
  f32x4 zero = {0.f, 0.f, 0.f, 0.f};
  #pragma unroll
  for (int m = 0; m < 4; ++m)
    #pragma unroll
    for (int n = 0; n < 4; ++n) acc[m][n] = zero;

  float sqa[4] = {0.f, 0.f, 0.f, 0.f};
  float sqb[4] = {0.f, 0.f, 0.f, 0.f};

  // staging geometry (per lane): wave stages rows [wave*32, wave*32+32)
  int srow = (wave << 5) + (lane >> 3);            // + j*8
  int pg = (lane & 7) ^ ((srow & 3) << 1);         // swizzled source piece
  const float* gA = Ag + (size_t)srow * 256 + pg * 4;
  const float* gB = Bg + (size_t)srow * 256 + pg * 4;
  int laneByte = lane * 16;                        // fallback only
  float* lA = &As[(wave << 5) * 32];               // wave-uniform LDS base
  float* lB = &Bs[(wave << 5) * 32];

  for (int k0 = 0; k0 < 8; ++k0) {
    #pragma unroll
    for (int j = 0; j < 4; ++j) {
      dma16(gA + j * 2048 + k0 * 32, lA + j * 8 * 32, laneByte);
      dma16(gB + j * 2048 + k0 * 32, lB + j * 8 * 32, laneByte);
    }
    __syncthreads();   // drains vmcnt (DMA) before fragment reads
    short8 af[4], bfr[4];
    #pragma unroll
    for (int m = 0; m < 4; ++m) {
      int r = wr + m * 16 + (lane & 15);
      int c = (lane >> 4) ^ (r & 3);
      float4 a0 = *(const float4*)&As[r * 32 + c * 8];
      float4 a1 = *(const float4*)&As[r * 32 + c * 8 + 4];
      sqa[m] += a0.x*a0.x + a0.y*a0.y + a0.z*a0.z + a0.w*a0.w
              + a1.x*a1.x + a1.y*a1.y + a1.z*a1.z + a1.w*a1.w;
      af[m] = cvt8f(a0, a1);
    }
    #pragma unroll
    for (int n = 0; n < 4; ++n) {
      int r = wc + n * 16 + (lane & 15);
      int c = (lane >> 4) ^ (r & 3);
      float4 b0 = *(const float4*)&Bs[r * 32 + c * 8];
      float4 b1 = *(const float4*)&Bs[r * 32 + c * 8 + 4];
      sqb[n] += b0.x*b0.x + b0.y*b0.y + b0.z*b0.z + b0.w*b0.w
              + b1.x*b1.x + b1.y*b1.y + b1.z*b1.z + b1.w*b1.w;
      bfr[n] = cvt8f(b0, b1);
    }
    #pragma unroll
    for (int m = 0; m < 4; ++m)
      #pragma unroll
      for (int n = 0; n < 4; ++n)
        acc[m][n] = __builtin_amdgcn_mfma_f32_16x16x32_bf16(bfr[n], af[m], acc[m][n], 0, 0, 0);
    __syncthreads();   // tile consumed; safe to overwrite next round
  }

  // complete row sumsq: 4 lanes (lane>>4 groups) tile each row's k-chunks
  #pragma unroll
  for (int m = 0; m < 4; ++m) {
    sqa[m] += __shfl_xor(sqa[m], 16, 64);
    sqa[m] += __shfl_xor(sqa[m], 32, 64);
    sqb[m] += __shfl_xor(sqb[m], 16, 64);
    sqb[m] += __shfl_xor(sqb[m], 32, 64);
  }
  if ((lane >> 4) == 0) {
    #pragma unroll
    for (int n = 0; n < 4; ++n) bsq[wc + n * 16 + (lane & 15)] = sqb[n];
  }
  __syncthreads();

  // epilogue (R12-proven): cos -> kv -> packed u32 fp8 direct to global
  float ira[4];
  #pragma unroll
  for (int m = 0; m < 4; ++m) ira[m] = rsqf_(sqa[m]);
  float irb[4][4];
  #pragma unroll
  for (int n = 0; n < 4; ++n)
    #pragma unroll
    for (int q = 0; q < 4; ++q)
      irb[n][q] = rsqf_(bsq[wc + n * 16 + ((lane >> 4) << 2) + q]);
  float csn[4][4];
  #pragma unroll
  for (int n = 0; n < 4; ++n)
    #pragma unroll
    for (int q = 0; q < 4; ++q) csn[n][q] = 0.f;
  size_t kbase = ((size_t)b << 20);
  #pragma unroll
  for (int m = 0; m < 4; ++m) {
    size_t rowoff = kbase + (size_t)(ti + wr + m * 16 + (lane & 15)) * 1024 + tj + wc + ((lane >> 4) << 2);
    #pragma unroll
    for (int n = 0; n < 4; ++n) {
      float kv[4];
      #pragma unroll
      for (int q = 0; q < 4; ++q) {
        float cosv = acc[m][n][q] * ira[m] * irb[n][q];
        kv[q] = __expf(cosv - 1.0f);
        csn[n][q] += kv[q];
      }
      unsigned pk = pack4fp8(kv[0], kv[1], kv[2], kv[3]);
      float kd[4];
      unpack4fp8(pk, kd);
      float rr[4];
      #pragma unroll
      for (int q = 0; q < 4; ++q) rr[q] = kv[q] * rcpf_(kd[q]) - 1.0f;
      unsigned pr = pack4fp8(rr[0], rr[1], rr[2], rr[3]);
      *(unsigned*)(K8g + rowoff + n * 16) = pk;
      *(unsigned*)(R8g + rowoff + n * 16) = pr;
    }
  }
  // column sums over the 16 rows per wave quadrant (lanes differing in bits 0-3)
  #pragma unroll
  for (int n = 0; n < 4; ++n)
    #pragma unroll
    for (int q = 0; q < 4; ++q) {
      float c_ = csn[n][q];
      c_ += __shfl_xor(c_, 1, 64);
      c_ += __shfl_xor(c_, 2, 64);
      c_ += __shfl_xor(c_, 4, 64);
      c_ += __shfl_xor(c_, 8, 64);
      if ((lane & 15) == 0)
        csum[wave][wc + n * 16 + ((lane >> 4) << 2) + q] = c_;
    }
  __syncthreads();
  if (t < 128) {
    float s_ = csum[t >> 6][t] + csum[2 + (t >> 6)][t];
    p0[((size_t)b << 13) + ((size_t)(ti >> 7) << 10) + tj + t] = (_Float16)s_;
  }
}

// ---------------------------------------------------------------- fused1024
// fp8-only pass: 16 waves/block (4 waves/SIMD), batch-2 + SW prefetch.
template<int BSHIFT, int NSRC>
__global__ __launch_bounds__(1024) void fused1024_kernel(
    const unsigned char* __restrict__ K8, const _Float16* __restrict__ src,
    _Float16* __restrict__ dst) {
  int bid = blockIdx.x;
  int b = bid >> 2, s = bid & 3;
  int t = threadIdx.x, lane = t & 63, w = t >> 6;
  __shared__ float sv[1024];
  __shared__ float plds[8][1024];  // 32 KB
  {
    int col = t;
    const _Float16* sp = src + ((size_t)b << BSHIFT) + col;
    float y = 0.f;
    #pragma unroll
    for (int j = 0; j < NSRC; ++j) y += (float)sp[j << 10];
    sv[col] = W1 / (y + EPSV);
  }
  __syncthreads();
  float svr[16];
  {
    float4 s0 = *(const float4*)&sv[lane * 16];
    float4 s1 = *(const float4*)&sv[lane * 16 + 4];
    float4 s2 = *(const float4*)&sv[lane * 16 + 8];
    float4 s3 = *(const float4*)&sv[lane * 16 + 12];
    svr[0] = s0.x;  svr[1] = s0.y;  svr[2]  = s0.z;  svr[3]  = s0.w;
    svr[4] = s1.x;  svr[5] = s1.y;  svr[6]  = s1.z;  svr[7]  = s1.w;
    svr[8] = s2.x;  svr[9] = s2.y;  svr[10] = s2.z;  svr[11] = s2.w;
    svr[12] = s3.x; svr[13] = s3.y; svr[14] = s3.z;  svr[15] = s3.w;
  }
  float pacc[16];
  #pragma unroll
  for (int k = 0; k < 16; ++k) pacc[k] = 0.f;
  const unsigned char* kp = K8 + ((size_t)b << 20) + (size_t)(s * 256 + w) * 1024 + lane * 16;
  uint4 c0 = *(const uint4*)(kp);
  uint4 c1 = *(const uint4*)(kp + 16384);
  for (int p = 0; p < 8; ++p) {
    uint4 n0, n1_;
    if (p < 7) {
      n0 = *(const uint4*)(kp + (size_t)(2 * p + 2) * 16384);
      n1_ = *(const uint4*)(kp + (size_t)(2 * p + 3) * 16384);
    }
    float d0 = dot16u(c0, svr);
    float d1 = dot16u(c1, svr);
    #pragma unroll
    for (int off = 1; off < 64; off <<= 1) {
      d0 += __shfl_xor(d0, off, 64);
      d1 += __shfl_xor(d1, off, 64);
    }
    float u0 = W1 / (d0 + EPSV);
    float u1 = W1 / (d1 + EPSV);
    axpy16u(c0, u0, pacc);
    axpy16u(c1, u1, pacc);
    c0 = n0; c1 = n1_;
  }
  if (w < 8) {
    *(float4*)&plds[w][lane * 16]      = *(float4*)&pacc[0];
    *(float4*)&plds[w][lane * 16 + 4]  = *(float4*)&pacc[4];
    *(float4*)&plds[w][lane * 16 + 8]  = *(float4*)&pacc[8];
    *(float4*)&plds[w][lane * 16 + 12] = *(float4*)&pacc[12];
  }
  __syncthreads();
  if (w >= 8) {
    float* pl = &plds[w - 8][lane * 16];
    #pragma unroll
    for (int k = 0; k < 16; ++k) pl[k] += pacc[k];
  }
  __syncthreads();
  {
    int col = t;
    float sum = 0.f;
    #pragma unroll
    for (int i = 0; i < 8; ++i) sum += plds[i][col];
    dst[((size_t)b << 12) + (s << 10) + col] = (_Float16)sum;
  }
}

// ---------------------------------------------------------------- fused512 (FINAL recon pass)
template<int FINAL>
__global__ __launch_bounds__(512) void fused512_kernel(
    const unsigned char* __restrict__ K8, const unsigned char* __restrict__ R8,
    const _Float16* __restrict__ src, _Float16* __restrict__ dst,
    float* __restrict__ zb, unsigned* __restrict__ mm) {
  int bid = blockIdx.x;
  int b = bid >> 2, s = bid & 3;
  int t = threadIdx.x, lane = t & 63, w = t >> 6;
  __shared__ float sv[1024];
  __shared__ float plds[8][1024];  // 32 KB
  __shared__ float red[16];
  #pragma unroll
  for (int p = 0; p < 2; ++p) {
    int col = (p << 9) + t;
    const _Float16* sp = src + ((size_t)b << 12) + col;
    float y = (float)sp[0] + (float)sp[1024] + (float)sp[2048] + (float)sp[3072];
    sv[col] = W1 / (y + EPSV);
  }
  __syncthreads();
  float svr[16];
  {
    float4 s0 = *(const float4*)&sv[lane * 16];
    float4 s1 = *(const float4*)&sv[lane * 16 + 4];
    float4 s2 = *(const float4*)&sv[lane * 16 + 8];
    float4 s3 = *(const float4*)&sv[lane * 16 + 12];
    svr[0] = s0.x;  svr[1] = s0.y;  svr[2]  = s0.z;  svr[3]  = s0.w;
    svr[4] = s1.x;  svr[5] = s1.y;  svr[6]  = s1.z;  svr[7]  = s1.w;
    svr[8] = s2.x;  svr[9] = s2.y;  svr[10] = s2.z;  svr[11] = s2.w;
    svr[12] = s3.x; svr[13] = s3.y; svr[14] = s3.z;  svr[15] = s3.w;
  }
  float pacc[16];
  #pragma unroll
  for (int k = 0; k < 16; ++k) pacc[k] = 0.f;
  float gmn = 3.4e38f, gmx = 0.f;
  const unsigned char* kp = K8 + ((size_t)b << 20) + (size_t)(s * 256 + w) * 1024 + lane * 16;
  const unsigned char* rp = R8 + ((size_t)b << 20) + (size_t)(s * 256 + w) * 1024 + lane * 16;
  uint4 c0 = *(const uint4*)(kp);
  uint4 c1 = *(const uint4*)(kp + 8192);
  uint4 r0 = *(const uint4*)(rp);
  uint4 r1 = *(const uint4*)(rp + 8192);
  for (int p = 0; p < 16; ++p) {
    uint4 n0, n1_, q0, q1;
    if (p < 15) {
      n0 = *(const uint4*)(kp + (size_t)(2 * p + 2) * 8192);
      n1_ = *(const uint4*)(kp + (size_t)(2 * p + 3) * 8192);
      q0 = *(const uint4*)(rp + (size_t)(2 * p + 2) * 8192);
      q1 = *(const uint4*)(rp + (size_t)(2 * p + 3) * 8192);
    }
    float kf0[16], kf1[16];
    decode16(c0, kf0);
    decode16(c1, kf1);
    {
      float rf0[16], rf1[16];
      decode16(r0, rf0);
      decode16(r1, rf1);
      #pragma unroll
      for (int k = 0; k < 16; ++k) {
        kf0[k] *= (1.0f + rf0[k]);
        kf1[k] *= (1.0f + rf1[k]);
      }
    }
    float d0 = 0.f, d1 = 0.f;
    #pragma unroll
    for (int k = 0; k < 16; ++k) {
      d0 += kf0[k] * svr[k];
      d1 += kf1[k] * svr[k];
    }
    #pragma unroll
    for (int off = 1; off < 64; off <<= 1) {
      d0 += __shfl_xor(d0, off, 64);
      d1 += __shfl_xor(d1, off, 64);
    }
    float u0 = W1 / (d0 + EPSV);
    float u1 = W1 / (d1 + EPSV);
    if (FINAL) {
      if (lane == 0) {
        zb[(b << 10) + s * 256 + w + (2 * p) * 8] = d0;
        zb[(b << 10) + s * 256 + w + (2 * p + 1) * 8] = d1;
      }
      #pragma unroll
      for (int k = 0; k < 16; ++k) {
        float g0 = u0 * kf0[k] * svr[k];
        float g1 = u1 * kf1[k] * svr[k];
        gmn = fminf(gmn, fminf(g0, g1));
        gmx = fmaxf(gmx, fmaxf(g0, g1));
      }
    } else {
      #pragma unroll
      for (int k = 0; k < 16; ++k)
        pacc[k] += kf0[k] * u0 + kf1[k] * u1;
    }
    c0 = n0; c1 = n1_; r0 = q0; r1 = q1;
  }
  if (!FINAL) {
    *(float4*)&plds[w][lane * 16]      = *(float4*)&pacc[0];
    *(float4*)&plds[w][lane * 16 + 4]  = *(float4*)&pacc[4];
    *(float4*)&plds[w][lane * 16 + 8]  = *(float4*)&pacc[8];
    *(float4*)&plds[w][lane * 16 + 12] = *(float4*)&pacc[12];
    __syncthreads();
    #pragma unroll
    for (int p = 0; p < 2; ++p) {
      int col = (p << 9) + t;
      float sum = plds[0][col] + plds[1][col] + plds[2][col] + plds[3][col]
                + plds[4][col] + plds[5][col] + plds[6][col] + plds[7][col];
      dst[((size_t)b << 12) + (s << 10) + col] = (_Float16)sum;
    }
  } else {
    #pragma unroll
    for (int off = 1; off < 64; off <<= 1) {
      gmn = fminf(gmn, __shfl_xor(gmn, off, 64));
      gmx = fmaxf(gmx, __shfl_xor(gmx, off, 64));
    }
    if (lane == 0) { red[w] = gmn; red[8 + w] = gmx; }
    __syncthreads();
    if (t == 0) {
      float m0 = red[0], m1 = red[8];
      #pragma unroll
      for (int i = 1; i < 8; ++i) { m0 = fminf(m0, red[i]); m1 = fmaxf(m1, red[8 + i]); }
      atomicMin(&mm[64 + b], __float_as_uint(m0));  // positive floats: uint order ok
      atomicMax(&mm[b],      __float_as_uint(m1));
    }
  }
}

// ---------------------------------------------------------------- fin
__global__ __launch_bounds__(256) void fin_kernel(
    const unsigned char* __restrict__ K8, const unsigned char* __restrict__ R8,
    const _Float16* __restrict__ src, const float* __restrict__ zb,
    const unsigned* __restrict__ mm, float* __restrict__ out) {
  int bid = blockIdx.x;
  int b = bid >> 4, rg = bid & 15;
  int t = threadIdx.x, lane = t & 63, w = t >> 6;
  __shared__ float sv[1024];
  #pragma unroll
  for (int p = 0; p < 4; ++p) {
    int col = (p << 8) + t;
    const _Float16* sp = src + ((size_t)b << 12) + col;
    float y = (float)sp[0] + (float)sp[1024] + (float)sp[2048] + (float)sp[3072];
    sv[col] = W1 / (y + EPSV);
  }
  __syncthreads();
  float svr[16];
  {
    float4 s0 = *(const float4*)&sv[lane * 16];
    float4 s1 = *(const float4*)&sv[lane * 16 + 4];
    float4 s2 = *(const float4*)&sv[lane * 16 + 8];
    float4 s3 = *(const float4*)&sv[lane * 16 + 12];
    svr[0] = s0.x;  svr[1] = s0.y;  svr[2]  = s0.z;  svr[3]  = s0.w;
    svr[4] = s1.x;  svr[5] = s1.y;  svr[6]  = s1.z;  svr[7]  = s1.w;
    svr[8] = s2.x;  svr[9] = s2.y;  svr[10] = s2.z;  svr[11] = s2.w;
    svr[12] = s3.x; svr[13] = s3.y; svr[14] = s3.z;  svr[15] = s3.w;
  }
  float gmx = __uint_as_float(mm[b]);
  float gmn = __uint_as_float(mm[64 + b]);
  float scale = 1.0f / (gmx - gmn + EPSV);
  const unsigned char* kp = K8 + ((size_t)b << 20) + (size_t)(rg * 64 + w) * 1024 + lane * 16;
  const unsigned char* rp = R8 + ((size_t)b << 20) + (size_t)(rg * 64 + w) * 1024 + lane * 16;
  float* op = out + ((size_t)b << 20) + (size_t)(rg * 64 + w) * 1024 + lane * 16;
  for (int it = 0; it < 16; ++it) {
    int r = rg * 64 + w + it * 4;
    float u = W1 / (zb[b * 1024 + r] + EPSV);
    uint4 dk = *(const uint4*)(kp + (size_t)it * 4096);
    uint4 dr = *(const uint4*)(rp + (size_t)it * 4096);
    float kf[16], rf[16], o[16];
    decode16(dk, kf);
    decode16(dr, rf);
    #pragma unroll
    for (int k = 0; k < 16; ++k) {
      float krec = kf[k] * (1.0f + rf[k]);
      float g = u * krec * svr[k];
      o[k] = (g - gmn) * scale * (-__logf(krec));
    }
    *(float4*)(op + (size_t)it * 4096)      = *(float4*)&o[0];
    *(float4*)(op + (size_t)it * 4096 + 4)  = *(float4*)&o[4];
    *(float4*)(op + (size_t)it * 4096 + 8)  = *(float4*)&o[8];
    *(float4*)(op + (size_t)it * 4096 + 12) = *(float4*)&o[12];
  }
}

// ---------------------------------------------------------------- launch
extern "C" void kernel_launch(void* const* d_in, const int* in_sizes, int n_in,
                              void* d_out, int out_size, void* d_ws, size_t ws_size,
                              hipStream_t stream) {
  const float* x1 = (const float*)d_in[0];
  const float* x2 = (const float*)d_in[1];
  float* out = (float*)d_out;
  char* ws = (char*)d_ws;

  // ws layout (bytes). p0 (1MB, 8-strip init partials) ALIASES [zb .. pB):
  // p0 written by gemm, read only by pass 1; zb written only by pass 10;
  // pA first written by pass 2 -> no temporal overlap.
  unsigned char* K8g = (unsigned char*)ws;                 // 67108864
  unsigned char* R8g = (unsigned char*)(ws + 67108864ULL); // 67108864
  float*    zb = (float*)(ws + 134217728ULL);              // 262144
  _Float16* p0 = (_Float16*)(ws + 134217728ULL);           // 1048576 (alias)
  _Float16* pA = (_Float16*)(ws + 134742016ULL);           // 524288
  _Float16* pB = (_Float16*)(ws + 135266304ULL);           // 524288
  unsigned* mm = (unsigned*)(ws + 135790592ULL);           // 512
  const size_t WS_NEED = 135791104ULL;                     // <= proven 136053248

  if (ws_size < WS_NEED) {
    float val = 100.0f + (float)(ws_size >> 20);
    diag_kernel<<<2048, 256, 0, stream>>>(out, val, out_size);
    return;
  }

  gemm_kernel<<<4096, 256, 0, stream>>>(x1, x2, K8g, R8g, mm, p0);
  // pass 1: src = p0 (8 strips), dst = pB
  fused1024_kernel<13, 8><<<256, 1024, 0, stream>>>(K8g, p0, pB);
  // passes 2..9: 4-strip ping-pong (all fp8-only); after pass 9 partials in pB
  for (int k = 2; k <= 9; ++k) {
    _Float16* src = (k & 1) ? pA : pB;
    _Float16* dst = (k & 1) ? pB : pA;
    fused1024_kernel<12, 4><<<256, 1024, 0, stream>>>(K8g, src, dst);
  }
  // pass 10 FINAL: reconstructed K; writes zb + minmax only (src pB = p9)
  fused512_kernel<1><<<256, 512, 0, stream>>>(K8g, R8g, pB, pA, zb, mm);
  fin_kernel<<<1024, 256, 0, stream>>>(K8g, R8g, pB, zb, mm, out);
}

// Round 14
// 434.238 us; speedup vs baseline: 1.0690x; 1.0690x over previous
//
#include <hip/hip_runtime.h>
#include <hip/hip_bf16.h>
#include <hip/hip_fp8.h>

// Sinkhorn on MI355X. B=64, L=1024, D=256.
// K stored as fp8-e4m3 plane K8 (64MB) + fp8 relative-residual plane R8 (64MB):
//   K_rec = dec(K8) * (1 + dec(R8))  ~= fp16 accuracy (0.2%).
// gemm (R12-proven: bf16 LDS staging, swapped-operand MFMA, packed-u32 fp8
//   direct stores, fused norms + colsum p0)
//   -> passes 1..9 fused1024 (fp8-only; pass1 reads 8-strip p0, rest 4-strip)
//   -> pass 10 fused1024F reconstructed (z + G minmax, 16 waves/block)
//   -> fin (out = minmax-norm(u*K_rec*v^T) * (-log K_rec))
// R14: revert gemm to R12 (R13's fp32-DMA had unavoidable 4-way LDS read
// conflicts); keep R13 schedule; pass10 upgraded 512->1024 threads.
// WS_NEED = 135791104 <= proven-available 136053248.

#define EPSV 1e-12f
#define W1 0.0009765625f   // 1/1024

typedef short  short8 __attribute__((ext_vector_type(8)));
typedef float  f32x4  __attribute__((ext_vector_type(4)));
typedef float  f32x2v __attribute__((ext_vector_type(2)));

// ---- fast math helpers ----
__device__ __forceinline__ float rcpf_(float x) {
#if __has_builtin(__builtin_amdgcn_rcpf)
  return __builtin_amdgcn_rcpf(x);
#else
  return 1.0f / x;
#endif
}
__device__ __forceinline__ float rsqf_(float x) {
#if __has_builtin(__builtin_amdgcn_rsqf)
  return __builtin_amdgcn_rsqf(x);
#else
  return rsqrtf(x);
#endif
}

// ---- fp8 e4m3 helpers ----
__device__ __forceinline__ unsigned char enc1(float x) {
#if __has_builtin(__builtin_amdgcn_cvt_pk_fp8_f32)
  int v = __builtin_amdgcn_cvt_pk_fp8_f32(x, x, 0, false);
  return (unsigned char)(v & 0xff);
#else
  __hip_fp8_e4m3 q(x); return (unsigned char)q.__x;
#endif
}
__device__ __forceinline__ float dec1(unsigned char b) {
#if __has_builtin(__builtin_amdgcn_cvt_f32_fp8)
  return __builtin_amdgcn_cvt_f32_fp8((int)b, 0);
#else
  __hip_fp8_e4m3 q; q.__x = (__hip_fp8_storage_t)b; return (float)q;
#endif
}
__device__ __forceinline__ unsigned pack4fp8(float a, float b, float c, float d) {
#if __has_builtin(__builtin_amdgcn_cvt_pk_fp8_f32)
  int v = __builtin_amdgcn_cvt_pk_fp8_f32(a, b, 0, false);
  v = __builtin_amdgcn_cvt_pk_fp8_f32(c, d, v, true);
  return (unsigned)v;
#else
  return (unsigned)enc1(a) | ((unsigned)enc1(b) << 8) |
         ((unsigned)enc1(c) << 16) | ((unsigned)enc1(d) << 24);
#endif
}
__device__ __forceinline__ void unpack4fp8(unsigned v, float* f) {
#if __has_builtin(__builtin_amdgcn_cvt_pk_f32_fp8)
  f32x2v p;
  p = __builtin_amdgcn_cvt_pk_f32_fp8((int)v, false); f[0] = p[0]; f[1] = p[1];
  p = __builtin_amdgcn_cvt_pk_f32_fp8((int)v, true);  f[2] = p[0]; f[3] = p[1];
#else
  #pragma unroll
  for (int i = 0; i < 4; ++i) f[i] = dec1((unsigned char)((v >> (i * 8)) & 0xff));
#endif
}
__device__ __forceinline__ void decode16(uint4 d, float* f) {
  unpack4fp8(d.x, f); unpack4fp8(d.y, f + 4);
  unpack4fp8(d.z, f + 8); unpack4fp8(d.w, f + 12);
}
__device__ __forceinline__ float dot16u(uint4 d, const float* s) {
#if __has_builtin(__builtin_amdgcn_cvt_pk_f32_fp8)
  f32x2v p; float a = 0.f;
  p = __builtin_amdgcn_cvt_pk_f32_fp8((int)d.x, false); a += p[0]*s[0]  + p[1]*s[1];
  p = __builtin_amdgcn_cvt_pk_f32_fp8((int)d.x, true);  a += p[0]*s[2]  + p[1]*s[3];
  p = __builtin_amdgcn_cvt_pk_f32_fp8((int)d.y, false); a += p[0]*s[4]  + p[1]*s[5];
  p = __builtin_amdgcn_cvt_pk_f32_fp8((int)d.y, true);  a += p[0]*s[6]  + p[1]*s[7];
  p = __builtin_amdgcn_cvt_pk_f32_fp8((int)d.z, false); a += p[0]*s[8]  + p[1]*s[9];
  p = __builtin_amdgcn_cvt_pk_f32_fp8((int)d.z, true);  a += p[0]*s[10] + p[1]*s[11];
  p = __builtin_amdgcn_cvt_pk_f32_fp8((int)d.w, false); a += p[0]*s[12] + p[1]*s[13];
  p = __builtin_amdgcn_cvt_pk_f32_fp8((int)d.w, true);  a += p[0]*s[14] + p[1]*s[15];
  return a;
#else
  float f[16]; decode16(d, f);
  float a = 0.f;
  #pragma unroll
  for (int k = 0; k < 16; ++k) a += f[k] * s[k];
  return a;
#endif
}
__device__ __forceinline__ void axpy16u(uint4 d, float u, float* pacc) {
#if __has_builtin(__builtin_amdgcn_cvt_pk_f32_fp8)
  f32x2v p;
  p = __builtin_amdgcn_cvt_pk_f32_fp8((int)d.x, false); pacc[0]  += p[0]*u; pacc[1]  += p[1]*u;
  p = __builtin_amdgcn_cvt_pk_f32_fp8((int)d.x, true);  pacc[2]  += p[0]*u; pacc[3]  += p[1]*u;
  p = __builtin_amdgcn_cvt_pk_f32_fp8((int)d.y, false); pacc[4]  += p[0]*u; pacc[5]  += p[1]*u;
  p = __builtin_amdgcn_cvt_pk_f32_fp8((int)d.y, true);  pacc[6]  += p[0]*u; pacc[7]  += p[1]*u;
  p = __builtin_amdgcn_cvt_pk_f32_fp8((int)d.z, false); pacc[8]  += p[0]*u; pacc[9]  += p[1]*u;
  p = __builtin_amdgcn_cvt_pk_f32_fp8((int)d.z, true);  pacc[10] += p[0]*u; pacc[11] += p[1]*u;
  p = __builtin_amdgcn_cvt_pk_f32_fp8((int)d.w, false); pacc[12] += p[0]*u; pacc[13] += p[1]*u;
  p = __builtin_amdgcn_cvt_pk_f32_fp8((int)d.w, true);  pacc[14] += p[0]*u; pacc[15] += p[1]*u;
#else
  float f[16]; decode16(d, f);
  #pragma unroll
  for (int k = 0; k < 16; ++k) pacc[k] += f[k] * u;
#endif
}

// load 8 consecutive floats, convert to 8 bf16; also accumulate sum of squares
__device__ __forceinline__ short8 ld_cvt8_sq(const float* p, float* sq) {
  float4 f0 = *(const float4*)p;
  float4 f1 = *(const float4*)(p + 4);
  *sq += f0.x * f0.x + f0.y * f0.y + f0.z * f0.z + f0.w * f0.w
       + f1.x * f1.x + f1.y * f1.y + f1.z * f1.z + f1.w * f1.w;
  float2 p0; p0.x = f0.x; p0.y = f0.y;
  float2 p1; p1.x = f0.z; p1.y = f0.w;
  float2 p2; p2.x = f1.x; p2.y = f1.y;
  float2 p3; p3.x = f1.z; p3.y = f1.w;
  __hip_bfloat162 h0 = __float22bfloat162_rn(p0);
  __hip_bfloat162 h1 = __float22bfloat162_rn(p1);
  __hip_bfloat162 h2_ = __float22bfloat162_rn(p2);
  __hip_bfloat162 h3 = __float22bfloat162_rn(p3);
  short2 a = *(short2*)&h0, b = *(short2*)&h1, c = *(short2*)&h2_, d = *(short2*)&h3;
  short8 r;
  r[0] = a.x; r[1] = a.y; r[2] = b.x; r[3] = b.y;
  r[4] = c.x; r[5] = c.y; r[6] = d.x; r[7] = d.y;
  return r;
}

// ---------------------------------------------------------------- diag
__global__ __launch_bounds__(256) void diag_kernel(float* __restrict__ out,
                                                   float val, int n) {
  int stride = gridDim.x * 256;
  for (int i = blockIdx.x * 256 + threadIdx.x; i < n; i += stride) out[i] = val;
}

// ---------------------------------------------------------------- gemm (R12-proven)
// 128x128 tile, BK=64, 4 waves (2x2 of 64x64), mfma_f32_16x16x32_bf16 with
// SWAPPED operands: acc[m][n][q] = K[ti + m*16 + (lane&15)]
//                                   [tj + n*16 + (lane>>4)*4 + q]
__global__ __launch_bounds__(256) void gemm_kernel(
    const float* __restrict__ x1, const float* __restrict__ x2,
    unsigned char* __restrict__ K8g, unsigned char* __restrict__ R8g,
    unsigned* __restrict__ mm, _Float16* __restrict__ p0) {
  __shared__ __align__(16) unsigned short smem[2 * 128 * 64];  // 32 KB
  __shared__ float asq[128], bsq[128];
  __shared__ float csum[4][128];
  unsigned short* As = smem;
  unsigned short* Bs = smem + 128 * 64;
  int bid = blockIdx.x;
  int b = bid >> 6, tile = bid & 63;
  int ti = (tile >> 3) << 7, tj = (tile & 7) << 7;
  int t = threadIdx.x, lane = t & 63, wave = t >> 6;
  int wr = (wave >> 1) << 6, wc = (wave & 1) << 6;
  const float* Ag = x1 + ((size_t)(b * 1024 + ti)) * 256;
  const float* Bg = x2 + ((size_t)(b * 1024 + tj)) * 256;

  if (bid == 0 && t < 128) mm[t] = (t < 64) ? 0u : 0x7f800000u;

  f32x4 acc[4][4];
  f32x4 zero = {0.f, 0.f, 0.f, 0.f};
  #pragma unroll
  for (int m = 0; m < 4; ++m)
    #pragma unroll
    for (int n = 0; n < 4; ++n) acc[m][n] = zero;

  float sqa[4] = {0.f, 0.f, 0.f, 0.f};
  float sqb[4] = {0.f, 0.f, 0.f, 0.f};
  short8 ra[4], rb[4];
  #pragma unroll
  for (int c = 0; c < 4; ++c) {
    int ch = t + (c << 8); int row = ch >> 3, kg = ch & 7;
    ra[c] = ld_cvt8_sq(Ag + row * 256 + kg * 8, &sqa[c]);
    rb[c] = ld_cvt8_sq(Bg + row * 256 + kg * 8, &sqb[c]);
  }

  for (int k0 = 0; k0 < 4; ++k0) {
    __syncthreads();
    #pragma unroll
    for (int c = 0; c < 4; ++c) {
      int ch = t + (c << 8); int row = ch >> 3, kg = ch & 7;
      int kgs = kg ^ (row & 7);
      *(short8*)(As + row * 64 + kgs * 8) = ra[c];
      *(short8*)(Bs + row * 64 + kgs * 8) = rb[c];
    }
    __syncthreads();
    if (k0 < 3) {
      #pragma unroll
      for (int c = 0; c < 4; ++c) {
        int ch = t + (c << 8); int row = ch >> 3, kg = ch & 7;
        ra[c] = ld_cvt8_sq(Ag + row * 256 + (k0 + 1) * 64 + kg * 8, &sqa[c]);
        rb[c] = ld_cvt8_sq(Bg + row * 256 + (k0 + 1) * 64 + kg * 8, &sqb[c]);
      }
    }
    #pragma unroll
    for (int ks = 0; ks < 2; ++ks) {
      short8 af[4], bfr[4];
      #pragma unroll
      for (int m = 0; m < 4; ++m) {
        int row = wr + m * 16 + (lane & 15);
        int c16 = (ks << 2) + (lane >> 4);
        af[m] = *(const short8*)(As + row * 64 + ((c16 ^ (row & 7)) << 3));
      }
      #pragma unroll
      for (int n = 0; n < 4; ++n) {
        int row = wc + n * 16 + (lane & 15);
        int c16 = (ks << 2) + (lane >> 4);
        bfr[n] = *(const short8*)(Bs + row * 64 + ((c16 ^ (row & 7)) << 3));
      }
      #pragma unroll
      for (int m = 0; m < 4; ++m)
        #pragma unroll
        for (int n = 0; n < 4; ++n)
          acc[m][n] = __builtin_amdgcn_mfma_f32_16x16x32_bf16(bfr[n], af[m], acc[m][n], 0, 0, 0);
    }
  }
  __syncthreads();
  // fold per-thread sumsq into per-row norms: 8 threads share a row -> shfl
  #pragma unroll
  for (int c = 0; c < 4; ++c) {
    float sa = sqa[c], sb = sqb[c];
    sa += __shfl_xor(sa, 1, 64); sb += __shfl_xor(sb, 1, 64);
    sa += __shfl_xor(sa, 2, 64); sb += __shfl_xor(sb, 2, 64);
    sa += __shfl_xor(sa, 4, 64); sb += __shfl_xor(sb, 4, 64);
    if ((t & 7) == 0) {
      int row = (t + (c << 8)) >> 3;
      asq[row] = sa; bsq[row] = sb;
    }
  }
  __syncthreads();

  // epilogue: cos -> kv -> packed u32 fp8 (K8, R8) direct to global
  float ira[4];
  #pragma unroll
  for (int m = 0; m < 4; ++m)
    ira[m] = rsqf_(asq[wr + m * 16 + (lane & 15)]);
  float irb[4][4];
  #pragma unroll
  for (int n = 0; n < 4; ++n)
    #pragma unroll
    for (int q = 0; q < 4; ++q)
      irb[n][q] = rsqf_(bsq[wc + n * 16 + ((lane >> 4) << 2) + q]);
  float csn[4][4];
  #pragma unroll
  for (int n = 0; n < 4; ++n)
    #pragma unroll
    for (int q = 0; q < 4; ++q) csn[n][q] = 0.f;
  size_t kbase = ((size_t)b << 20);
  #pragma unroll
  for (int m = 0; m < 4; ++m) {
    size_t rowoff = kbase + (size_t)(ti + wr + m * 16 + (lane & 15)) * 1024 + tj + wc + ((lane >> 4) << 2);
    #pragma unroll
    for (int n = 0; n < 4; ++n) {
      float kv[4];
      #pragma unroll
      for (int q = 0; q < 4; ++q) {
        float cosv = acc[m][n][q] * ira[m] * irb[n][q];
        kv[q] = __expf(cosv - 1.0f);
        csn[n][q] += kv[q];
      }
      unsigned pk = pack4fp8(kv[0], kv[1], kv[2], kv[3]);
      float kd[4];
      unpack4fp8(pk, kd);
      float rr[4];
      #pragma unroll
      for (int q = 0; q < 4; ++q) rr[q] = kv[q] * rcpf_(kd[q]) - 1.0f;
      unsigned pr = pack4fp8(rr[0], rr[1], rr[2], rr[3]);
      *(unsigned*)(K8g + rowoff + n * 16) = pk;
      *(unsigned*)(R8g + rowoff + n * 16) = pr;
    }
  }
  // column sums: reduce over the 16 lanes sharing a column set (lane&15)
  #pragma unroll
  for (int n = 0; n < 4; ++n)
    #pragma unroll
    for (int q = 0; q < 4; ++q) {
      float c_ = csn[n][q];
      c_ += __shfl_xor(c_, 1, 64);
      c_ += __shfl_xor(c_, 2, 64);
      c_ += __shfl_xor(c_, 4, 64);
      c_ += __shfl_xor(c_, 8, 64);
      if ((lane & 15) == 0)
        csum[wave][wc + n * 16 + ((lane >> 4) << 2) + q] = c_;
    }
  __syncthreads();
  if (t < 128) {
    float s_ = csum[t >> 6][t] + csum[2 + (t >> 6)][t];
    p0[((size_t)b << 13) + ((size_t)(ti >> 7) << 10) + tj + t] = (_Float16)s_;
  }
}

// ---------------------------------------------------------------- fused1024
// fp8-only pass: 16 waves/block (4 waves/SIMD), batch-2 + SW prefetch.
template<int BSHIFT, int NSRC>
__global__ __launch_bounds__(1024) void fused1024_kernel(
    const unsigned char* __restrict__ K8, const _Float16* __restrict__ src,
    _Float16* __restrict__ dst) {
  int bid = blockIdx.x;
  int b = bid >> 2, s = bid & 3;
  int t = threadIdx.x, lane = t & 63, w = t >> 6;
  __shared__ float sv[1024];
  __shared__ float plds[8][1024];  // 32 KB
  {
    int col = t;
    const _Float16* sp = src + ((size_t)b << BSHIFT) + col;
    float y = 0.f;
    #pragma unroll
    for (int j = 0; j < NSRC; ++j) y += (float)sp[j << 10];
    sv[col] = W1 / (y + EPSV);
  }
  __syncthreads();
  float svr[16];
  {
    float4 s0 = *(const float4*)&sv[lane * 16];
    float4 s1 = *(const float4*)&sv[lane * 16 + 4];
    float4 s2 = *(const float4*)&sv[lane * 16 + 8];
    float4 s3 = *(const float4*)&sv[lane * 16 + 12];
    svr[0] = s0.x;  svr[1] = s0.y;  svr[2]  = s0.z;  svr[3]  = s0.w;
    svr[4] = s1.x;  svr[5] = s1.y;  svr[6]  = s1.z;  svr[7]  = s1.w;
    svr[8] = s2.x;  svr[9] = s2.y;  svr[10] = s2.z;  svr[11] = s2.w;
    svr[12] = s3.x; svr[13] = s3.y; svr[14] = s3.z;  svr[15] = s3.w;
  }
  float pacc[16];
  #pragma unroll
  for (int k = 0; k < 16; ++k) pacc[k] = 0.f;
  const unsigned char* kp = K8 + ((size_t)b << 20) + (size_t)(s * 256 + w) * 1024 + lane * 16;
  uint4 c0 = *(const uint4*)(kp);
  uint4 c1 = *(const uint4*)(kp + 16384);
  for (int p = 0; p < 8; ++p) {
    uint4 n0, n1_;
    if (p < 7) {
      n0 = *(const uint4*)(kp + (size_t)(2 * p + 2) * 16384);
      n1_ = *(const uint4*)(kp + (size_t)(2 * p + 3) * 16384);
    }
    float d0 = dot16u(c0, svr);
    float d1 = dot16u(c1, svr);
    #pragma unroll
    for (int off = 1; off < 64; off <<= 1) {
      d0 += __shfl_xor(d0, off, 64);
      d1 += __shfl_xor(d1, off, 64);
    }
    float u0 = W1 / (d0 + EPSV);
    float u1 = W1 / (d1 + EPSV);
    axpy16u(c0, u0, pacc);
    axpy16u(c1, u1, pacc);
    c0 = n0; c1 = n1_;
  }
  if (w < 8) {
    *(float4*)&plds[w][lane * 16]      = *(float4*)&pacc[0];
    *(float4*)&plds[w][lane * 16 + 4]  = *(float4*)&pacc[4];
    *(float4*)&plds[w][lane * 16 + 8]  = *(float4*)&pacc[8];
    *(float4*)&plds[w][lane * 16 + 12] = *(float4*)&pacc[12];
  }
  __syncthreads();
  if (w >= 8) {
    float* pl = &plds[w - 8][lane * 16];
    #pragma unroll
    for (int k = 0; k < 16; ++k) pl[k] += pacc[k];
  }
  __syncthreads();
  {
    int col = t;
    float sum = 0.f;
    #pragma unroll
    for (int i = 0; i < 8; ++i) sum += plds[i][col];
    dst[((size_t)b << 12) + (s << 10) + col] = (_Float16)sum;
  }
}

// ---------------------------------------------------------------- fused1024F
// FINAL recon pass at 16 waves/block: z = K_rec v -> zb; G minmax -> mm.
// No pacc/dst (final). Live regs ~90 < 128 cap.
__global__ __launch_bounds__(1024) void fused1024F_kernel(
    const unsigned char* __restrict__ K8, const unsigned char* __restrict__ R8,
    const _Float16* __restrict__ src, float* __restrict__ zb,
    unsigned* __restrict__ mm) {
  int bid = blockIdx.x;
  int b = bid >> 2, s = bid & 3;
  int t = threadIdx.x, lane = t & 63, w = t >> 6;
  __shared__ float sv[1024];
  __shared__ float red[32];
  {
    int col = t;
    const _Float16* sp = src + ((size_t)b << 12) + col;
    float y = (float)sp[0] + (float)sp[1024] + (float)sp[2048] + (float)sp[3072];
    sv[col] = W1 / (y + EPSV);
  }
  __syncthreads();
  float svr[16];
  {
    float4 s0 = *(const float4*)&sv[lane * 16];
    float4 s1 = *(const float4*)&sv[lane * 16 + 4];
    float4 s2 = *(const float4*)&sv[lane * 16 + 8];
    float4 s3 = *(const float4*)&sv[lane * 16 + 12];
    svr[0] = s0.x;  svr[1] = s0.y;  svr[2]  = s0.z;  svr[3]  = s0.w;
    svr[4] = s1.x;  svr[5] = s1.y;  svr[6]  = s1.z;  svr[7]  = s1.w;
    svr[8] = s2.x;  svr[9] = s2.y;  svr[10] = s2.z;  svr[11] = s2.w;
    svr[12] = s3.x; svr[13] = s3.y; svr[14] = s3.z;  svr[15] = s3.w;
  }
  float gmn = 3.4e38f, gmx = 0.f;
  const unsigned char* kp = K8 + ((size_t)b << 20) + (size_t)(s * 256 + w) * 1024 + lane * 16;
  const unsigned char* rp = R8 + ((size_t)b << 20) + (size_t)(s * 256 + w) * 1024 + lane * 16;
  for (int p = 0; p < 8; ++p) {
    uint4 c0 = *(const uint4*)(kp + (size_t)(2 * p) * 16384);
    uint4 c1 = *(const uint4*)(kp + (size_t)(2 * p + 1) * 16384);
    uint4 r0 = *(const uint4*)(rp + (size_t)(2 * p) * 16384);
    uint4 r1 = *(const uint4*)(rp + (size_t)(2 * p + 1) * 16384);
    float kf0[16], kf1[16], rf[16];
    decode16(c0, kf0);
    decode16(r0, rf);
    #pragma unroll
    for (int k = 0; k < 16; ++k) kf0[k] *= (1.0f + rf[k]);
    decode16(c1, kf1);
    decode16(r1, rf);
    #pragma unroll
    for (int k = 0; k < 16; ++k) kf1[k] *= (1.0f + rf[k]);
    float d0 = 0.f, d1 = 0.f;
    #pragma unroll
    for (int k = 0; k < 16; ++k) {
      d0 += kf0[k] * svr[k];
      d1 += kf1[k] * svr[k];
    }
    #pragma unroll
    for (int off = 1; off < 64; off <<= 1) {
      d0 += __shfl_xor(d0, off, 64);
      d1 += __shfl_xor(d1, off, 64);
    }
    float u0 = W1 / (d0 + EPSV);
    float u1 = W1 / (d1 + EPSV);
    if (lane == 0) {
      zb[(b << 10) + s * 256 + w + (2 * p) * 16] = d0;
      zb[(b << 10) + s * 256 + w + (2 * p + 1) * 16] = d1;
    }
    #pragma unroll
    for (int k = 0; k < 16; ++k) {
      float g0 = u0 * kf0[k] * svr[k];
      float g1 = u1 * kf1[k] * svr[k];
      gmn = fminf(gmn, fminf(g0, g1));
      gmx = fmaxf(gmx, fmaxf(g0, g1));
    }
  }
  #pragma unroll
  for (int off = 1; off < 64; off <<= 1) {
    gmn = fminf(gmn, __shfl_xor(gmn, off, 64));
    gmx = fmaxf(gmx, __shfl_xor(gmx, off, 64));
  }
  if (lane == 0) { red[w] = gmn; red[16 + w] = gmx; }
  __syncthreads();
  if (t == 0) {
    float m0 = red[0], m1 = red[16];
    #pragma unroll
    for (int i = 1; i < 16; ++i) { m0 = fminf(m0, red[i]); m1 = fmaxf(m1, red[16 + i]); }
    atomicMin(&mm[64 + b], __float_as_uint(m0));  // positive floats: uint order ok
    atomicMax(&mm[b],      __float_as_uint(m1));
  }
}

// ---------------------------------------------------------------- fin
__global__ __launch_bounds__(256) void fin_kernel(
    const unsigned char* __restrict__ K8, const unsigned char* __restrict__ R8,
    const _Float16* __restrict__ src, const float* __restrict__ zb,
    const unsigned* __restrict__ mm, float* __restrict__ out) {
  int bid = blockIdx.x;
  int b = bid >> 4, rg = bid & 15;
  int t = threadIdx.x, lane = t & 63, w = t >> 6;
  __shared__ float sv[1024];
  #pragma unroll
  for (int p = 0; p < 4; ++p) {
    int col = (p << 8) + t;
    const _Float16* sp = src + ((size_t)b << 12) + col;
    float y = (float)sp[0] + (float)sp[1024] + (float)sp[2048] + (float)sp[3072];
    sv[col] = W1 / (y + EPSV);
  }
  __syncthreads();
  float svr[16];
  {
    float4 s0 = *(const float4*)&sv[lane * 16];
    float4 s1 = *(const float4*)&sv[lane * 16 + 4];
    float4 s2 = *(const float4*)&sv[lane * 16 + 8];
    float4 s3 = *(const float4*)&sv[lane * 16 + 12];
    svr[0] = s0.x;  svr[1] = s0.y;  svr[2]  = s0.z;  svr[3]  = s0.w;
    svr[4] = s1.x;  svr[5] = s1.y;  svr[6]  = s1.z;  svr[7]  = s1.w;
    svr[8] = s2.x;  svr[9] = s2.y;  svr[10] = s2.z;  svr[11] = s2.w;
    svr[12] = s3.x; svr[13] = s3.y; svr[14] = s3.z;  svr[15] = s3.w;
  }
  float gmx = __uint_as_float(mm[b]);
  float gmn = __uint_as_float(mm[64 + b]);
  float scale = 1.0f / (gmx - gmn + EPSV);
  const unsigned char* kp = K8 + ((size_t)b << 20) + (size_t)(rg * 64 + w) * 1024 + lane * 16;
  const unsigned char* rp = R8 + ((size_t)b << 20) + (size_t)(rg * 64 + w) * 1024 + lane * 16;
  float* op = out + ((size_t)b << 20) + (size_t)(rg * 64 + w) * 1024 + lane * 16;
  for (int it = 0; it < 16; ++it) {
    int r = rg * 64 + w + it * 4;
    float u = W1 / (zb[b * 1024 + r] + EPSV);
    uint4 dk = *(const uint4*)(kp + (size_t)it * 4096);
    uint4 dr = *(const uint4*)(rp + (size_t)it * 4096);
    float kf[16], rf[16], o[16];
    decode16(dk, kf);
    decode16(dr, rf);
    #pragma unroll
    for (int k = 0; k < 16; ++k) {
      float krec = kf[k] * (1.0f + rf[k]);
      float g = u * krec * svr[k];
      o[k] = (g - gmn) * scale * (-__logf(krec));
    }
    *(float4*)(op + (size_t)it * 4096)      = *(float4*)&o[0];
    *(float4*)(op + (size_t)it * 4096 + 4)  = *(float4*)&o[4];
    *(float4*)(op + (size_t)it * 4096 + 8)  = *(float4*)&o[8];
    *(float4*)(op + (size_t)it * 4096 + 12) = *(float4*)&o[12];
  }
}

// ---------------------------------------------------------------- launch
extern "C" void kernel_launch(void* const* d_in, const int* in_sizes, int n_in,
                              void* d_out, int out_size, void* d_ws, size_t ws_size,
                              hipStream_t stream) {
  const float* x1 = (const float*)d_in[0];
  const float* x2 = (const float*)d_in[1];
  float* out = (float*)d_out;
  char* ws = (char*)d_ws;

  // ws layout (bytes). p0 (1MB, 8-strip init partials) ALIASES [zb .. pA):
  // p0 written by gemm, read only by pass 1; zb written only by pass 10;
  // pA first written by pass 2 -> no temporal overlap.
  unsigned char* K8g = (unsigned char*)ws;                 // 67108864
  unsigned char* R8g = (unsigned char*)(ws + 67108864ULL); // 67108864
  float*    zb = (float*)(ws + 134217728ULL);              // 262144
  _Float16* p0 = (_Float16*)(ws + 134217728ULL);           // 1048576 (alias)
  _Float16* pA = (_Float16*)(ws + 134742016ULL);           // 524288
  _Float16* pB = (_Float16*)(ws + 135266304ULL);           // 524288
  unsigned* mm = (unsigned*)(ws + 135790592ULL);           // 512
  const size_t WS_NEED = 135791104ULL;                     // <= proven 136053248

  if (ws_size < WS_NEED) {
    float val = 100.0f + (float)(ws_size >> 20);
    diag_kernel<<<2048, 256, 0, stream>>>(out, val, out_size);
    return;
  }

  gemm_kernel<<<4096, 256, 0, stream>>>(x1, x2, K8g, R8g, mm, p0);
  // pass 1: src = p0 (8 strips), dst = pB
  fused1024_kernel<13, 8><<<256, 1024, 0, stream>>>(K8g, p0, pB);
  // passes 2..9: 4-strip ping-pong (all fp8-only); after pass 9 partials in pB
  for (int k = 2; k <= 9; ++k) {
    _Float16* src = (k & 1) ? pA : pB;
    _Float16* dst = (k & 1) ? pB : pA;
    fused1024_kernel<12, 4><<<256, 1024, 0, stream>>>(K8g, src, dst);
  }
  // pass 10 FINAL: reconstructed K; writes zb + minmax (src pB = p9)
  fused1024F_kernel<<<256, 1024, 0, stream>>>(K8g, R8g, pB, zb, mm);
  fin_kernel<<<1024, 256, 0, stream>>>(K8g, R8g, pB, zb, mm, out);
}